// Round 8
// baseline (771.261 us; speedup 1.0000x reference)
//
#include <hip/hip_runtime.h>

// VectorQuantizer forward: out = codebook[argmin_k ||x - e_k||^2]
// R14: bf16 3-term (R10 numerics, proven ~0.1% fallback rate) + ILP
//      restructure. R13's fp16 bound forced a ~40x bigger fallback trigger
//      and its full-codebook uncoalesced gather (4x line amplification
//      through L2) cost >100us -> abandoned. R10's stall: per-ct serial
//      phases {4 ds_read -> wait -> two 6-deep MFMA chains -> argmin},
//      pipes never overlap (sum 12-15us vs 58us wall), occupancy-invariant.
//      Fix at the source level hipcc handles well (straight-line code with
//      counted lgkmcnt): FULL unroll of the 32-ct sweep (all LDS addresses
//      become base+immediate; compiler hoists reads across iterations) and
//      3-way accumulator split per (ct,rt): chains of 6 dependent MFMA ->
//      3 independent chains of 2 (+2 fp32 adds; score perturbation ~1e-7,
//      inside the TAU margin; committed argmins still exactly fp32 via the
//      unchanged near-tie fallback).

#define KC 512
#define DD 64
#define TAU 5e-4f
#define HTAU (0.5f * TAU)    // threshold in c-space (s = -2c)

typedef __attribute__((ext_vector_type(8))) short short8;
typedef __attribute__((ext_vector_type(4))) float float4v;

__device__ inline unsigned short f2bf(float f) {   // RNE bf16
    unsigned u = __float_as_uint(f);
    return (unsigned short)((u + 0x7FFF + ((u >> 16) & 1)) >> 16);
}
__device__ inline float bf2f(unsigned short b) {
    return __uint_as_float((unsigned)b << 16);
}

// Per code-tile ct (16 codes): bias (exact fp32, sequential d), et (fp32
// transposed codebook for gather/fallback), and Bh/Bl bf16 packs laid out in
// the exact 16x16x32 B-fragment order: element (lane l, j) = E[kc*32 +
// (l>>4)*8 + j][ct*16 + (l&15)].
__global__ __launch_bounds__(256) void vq_prep(const float* __restrict__ emb,
                                               float* __restrict__ et,
                                               float* __restrict__ bias,
                                               short* __restrict__ Bh,
                                               short* __restrict__ Bl) {
    __shared__ float tile[DD][17];
    const int ct = blockIdx.x;            // 0..31
    const int t  = threadIdx.x;

    {   // stage emb[d][ct*16..+16] -> tile[d][c]
        const int d = t >> 2, c0 = (t & 3) * 4;
        float4 v = *(const float4*)(emb + (size_t)d * KC + ct * 16 + c0);
        tile[d][c0 + 0] = v.x; tile[d][c0 + 1] = v.y;
        tile[d][c0 + 2] = v.z; tile[d][c0 + 3] = v.w;
    }
    __syncthreads();

    if (t < 16) {   // bias, exact sequential d-order
        float s = 0.f;
        #pragma unroll
        for (int d = 0; d < DD; ++d) { float v = tile[d][t]; s += v * v; }
        bias[ct * 16 + t] = s;
    }

    {   // et[(ct*16+c)][d0..d0+3]
        const int c = t >> 4, d0 = (t & 15) * 4;
        float4 v;
        v.x = tile[d0 + 0][c]; v.y = tile[d0 + 1][c];
        v.z = tile[d0 + 2][c]; v.w = tile[d0 + 3][c];
        *(float4*)(et + (size_t)(ct * 16 + c) * DD + d0) = v;
    }

    {   // B-fragment packs
        const int term = t >> 7;          // 0 = hi, 1 = lo
        const int kc   = (t >> 6) & 1;
        const int l    = t & 63;
        const int c    = l & 15, dq = l >> 4;
        short v8[8];
        #pragma unroll
        for (int j = 0; j < 8; ++j) {
            float f = tile[kc * 32 + dq * 8 + j][c];
            unsigned short h = f2bf(f);
            v8[j] = (short)(term == 0 ? h : f2bf(f - bf2f(h)));
        }
        short* dst = (term == 0 ? Bh : Bl) + ((size_t)(ct * 2 + kc) * 64 + l) * 8;
        *(short8*)dst = *(short8*)v8;
    }
}

// Block = 1024 threads / 16 waves, covers 512 rows; wave w owns rows
// [w*32, w*32+32) in registers and sweeps all 512 codes from LDS.
__global__ __launch_bounds__(1024, 4) void vq_main(const float* __restrict__ x_in,
                                                   const short* __restrict__ Bh,
                                                   const short* __restrict__ Bl,
                                                   const float* __restrict__ bias,
                                                   const float* __restrict__ et,
                                                   float* __restrict__ out) {
    __shared__ __align__(16) short Bh_lds[32 * 2 * 64 * 8];   // 64 KB
    __shared__ __align__(16) short Bl_lds[32 * 2 * 64 * 8];   // 64 KB
    __shared__ float bias_s[KC];                               // 2 KB
    __shared__ int   k1s[16][32];
    __shared__ float gaps[16][32];

    const int t = threadIdx.x, w = t >> 6, l = t & 63;
    const int col = l & 15, quad = l >> 4;
    const int R0 = blockIdx.x * 512;
    const int wrow0 = w * 32;

    {   // stage Bh/Bl/bias -> LDS (coalesced float4 copies)
        const float4* srcH = (const float4*)Bh;
        const float4* srcL = (const float4*)Bl;
        float4* dstH = (float4*)Bh_lds;
        float4* dstL = (float4*)Bl_lds;
        #pragma unroll
        for (int j = 0; j < 4; ++j) {
            const int idx = t + j * 1024;             // 4096 float4 per array
            dstH[idx] = srcH[idx];
            dstL[idx] = srcL[idx];
        }
        if (t < KC) bias_s[t] = bias[t];
    }

    // ---- A: this wave's 32 rows -> registers, bf16 hi/lo split (done once).
    // 16x16x32 A-layout: m = lane&15, k = quad*8 + j; rt = 16-row tile 0..1.
    short8 AH[2][2], AL[2][2];
    #pragma unroll
    for (int rt = 0; rt < 2; ++rt)
        #pragma unroll
        for (int kc = 0; kc < 2; ++kc) {
            const float* p = x_in + (size_t)(R0 + wrow0 + rt * 16 + col) * DD
                           + kc * 32 + quad * 8;
            float4 xa = *(const float4*)p;
            float4 xb = *(const float4*)(p + 4);
            float f[8] = {xa.x, xa.y, xa.z, xa.w, xb.x, xb.y, xb.z, xb.w};
            short8 hi8, lo8;
            #pragma unroll
            for (int j = 0; j < 8; ++j) {
                unsigned short h = f2bf(f[j]);
                hi8[j] = (short)h;
                lo8[j] = (short)f2bf(f[j] - bf2f(h));
            }
            AH[rt][kc] = hi8;
            AL[rt][kc] = lo8;
        }
    __syncthreads();   // B staged (the only block-wide barrier before reduce)

    // per-(row,code-lane) running max1/max2/k in c-space (c = x.e - b/2)
    float m1[2][4], m2[2][4];
    int   kb[2][4];
    #pragma unroll
    for (int rt = 0; rt < 2; ++rt)
        #pragma unroll
        for (int r = 0; r < 4; ++r) {
            m1[rt][r] = -3.4e38f; m2[rt][r] = -3.4e38f; kb[rt][r] = 0;
        }

    // ---- fully-unrolled sweep: straight-line body, all LDS addresses are
    // base+immediate; compiler hoists ds_reads across iterations with
    // counted lgkmcnt. 3 independent 2-chains per (ct,rt) keep the MFMA
    // pipe issue-bound instead of latency-bound.
    #pragma unroll
    for (int ct = 0; ct < 32; ++ct) {
        short8 bh0 = *(const short8*)&Bh_lds[((ct * 2 + 0) * 64 + l) * 8];
        short8 bh1 = *(const short8*)&Bh_lds[((ct * 2 + 1) * 64 + l) * 8];
        short8 bl0 = *(const short8*)&Bl_lds[((ct * 2 + 0) * 64 + l) * 8];
        short8 bl1 = *(const short8*)&Bl_lds[((ct * 2 + 1) * 64 + l) * 8];
        const float ci = -0.5f * bias_s[ct * 16 + col];
        const int kk = ct * 16 + col;
        #pragma unroll
        for (int rt = 0; rt < 2; ++rt) {
            float4v cA = {ci, ci, ci, ci};
            float4v cB = {0.f, 0.f, 0.f, 0.f};
            float4v cC = {0.f, 0.f, 0.f, 0.f};
            cA = __builtin_amdgcn_mfma_f32_16x16x32_bf16(AH[rt][0], bh0, cA, 0, 0, 0);
            cB = __builtin_amdgcn_mfma_f32_16x16x32_bf16(AL[rt][0], bh0, cB, 0, 0, 0);
            cC = __builtin_amdgcn_mfma_f32_16x16x32_bf16(AH[rt][0], bl0, cC, 0, 0, 0);
            cA = __builtin_amdgcn_mfma_f32_16x16x32_bf16(AH[rt][1], bh1, cA, 0, 0, 0);
            cB = __builtin_amdgcn_mfma_f32_16x16x32_bf16(AL[rt][1], bh1, cB, 0, 0, 0);
            cC = __builtin_amdgcn_mfma_f32_16x16x32_bf16(AH[rt][1], bl1, cC, 0, 0, 0);
            #pragma unroll
            for (int r = 0; r < 4; ++r) {
                float cr = (cA[r] + cB[r]) + cC[r];
                bool gt = cr > m1[rt][r];                    // strict: first-min k
                m2[rt][r] = fmaxf(fminf(cr, m1[rt][r]), m2[rt][r]);
                kb[rt][r] = gt ? kk : kb[rt][r];
                m1[rt][r] = fmaxf(m1[rt][r], cr);
            }
        }
    }

    // reduce over the 16 code-lanes (once per wave); C layout: row =
    // rt*16 + quad*4 + r, col = lane&15.
    #pragma unroll
    for (int rt = 0; rt < 2; ++rt)
        #pragma unroll
        for (int r = 0; r < 4; ++r) {
            float b1 = m1[rt][r], b2 = m2[rt][r];
            int   bk = kb[rt][r];
            #pragma unroll
            for (int m = 1; m <= 8; m <<= 1) {
                float o1 = __shfl_xor(b1, m, 64);
                float o2 = __shfl_xor(b2, m, 64);
                int   ok = __shfl_xor(bk, m, 64);
                float n2 = fmaxf(fmaxf(b2, o2), fminf(b1, o1));
                bool take = (o1 > b1) || (o1 == b1 && ok < bk);
                b1 = take ? o1 : b1;
                bk = take ? ok : bk;
                b2 = n2;
            }
            if (col == 0) {
                const int rowl = rt * 16 + quad * 4 + r;
                k1s[w][rowl]  = bk;
                gaps[w][rowl] = b1 - b2;     // c-space gap = s-gap / 2
            }
        }
    __syncthreads();   // make k1s/gaps visible (cheap, once)

    {   // exact fp32 fallback for near-tie rows (ballot-driven, rare).
        // Lane l scans codes [8l,8l+8) ascending; cross-lane tie-break =
        // lower k => numpy first-min semantics, independent of approx path.
        unsigned long long mask = __ballot((l < 32) && (gaps[w][l & 31] <= HTAU));
        mask &= 0xFFFFFFFFull;
        while (mask) {
            const int rr = __builtin_ctzll(mask);
            mask &= mask - 1;
            const size_t grow = (size_t)(R0 + wrow0 + rr) * DD;
            const int kbase = l * 8;
            float acc[8];
            #pragma unroll
            for (int j = 0; j < 8; ++j) acc[j] = 0.f;
            for (int d0 = 0; d0 < DD; d0 += 4) {
                float4 xv = *(const float4*)(x_in + grow + d0);
                #pragma unroll
                for (int j = 0; j < 8; ++j) {
                    float4 ev = *(const float4*)(et + (size_t)(kbase + j) * DD + d0);
                    acc[j] += xv.x * ev.x;
                    acc[j] += xv.y * ev.y;
                    acc[j] += xv.z * ev.z;
                    acc[j] += xv.w * ev.w;
                }
            }
            float4 b0 = *(const float4*)(bias + kbase);
            float4 b1v = *(const float4*)(bias + kbase + 4);
            float bb[8] = {b0.x, b0.y, b0.z, b0.w, b1v.x, b1v.y, b1v.z, b1v.w};
            float bv = 3.4e38f; int bk = 0;
            #pragma unroll
            for (int j = 0; j < 8; ++j) {
                float s = bb[j] - 2.f * acc[j];
                if (s < bv) { bv = s; bk = kbase + j; }
            }
            #pragma unroll
            for (int m = 1; m <= 32; m <<= 1) {
                float ov = __shfl_xor(bv, m, 64);
                int   ok = __shfl_xor(bk, m, 64);
                if (ov < bv || (ov == bv && ok < bk)) { bv = ov; bk = ok; }
            }
            if (l == 0) k1s[w][rr] = bk;
        }
    }

    {   // gather epilogue (per wave, its own rows): 16 lanes per row
        const int c4 = col * 4;
        #pragma unroll
        for (int i = 0; i < 8; ++i) {
            const int rowl = i * 4 + quad;
            const int bk = k1s[w][rowl];
            float4 v = *(const float4*)(et + (size_t)bk * DD + c4);
            *(float4*)(out + (size_t)(R0 + wrow0 + rowl) * DD + c4) = v;
        }
    }
}

extern "C" void kernel_launch(void* const* d_in, const int* in_sizes, int n_in,
                              void* d_out, int out_size, void* d_ws, size_t ws_size,
                              hipStream_t stream) {
    const float* x_in = (const float*)d_in[0];   // [131072, 64]
    const float* emb  = (const float*)d_in[1];   // [64, 512]
    float* out = (float*)d_out;

    float* et   = (float*)d_ws;                       // 512*64 f32 = 131072 B
    float* bias = et + KC * DD;                       // 2048 B
    short* Bh   = (short*)(bias + KC);                // 32*2*64*8 shorts = 64 KB
    short* Bl   = Bh + 32 * 2 * 64 * 8;               // 64 KB

    const int N = out_size / DD;                      // 131072 rows

    vq_prep<<<32, 256, 0, stream>>>(emb, et, bias, Bh, Bl);
    vq_main<<<N / 512, 1024, 0, stream>>>(x_in, Bh, Bl, bias, et, out);
}

// Round 9
// 140.538 us; speedup vs baseline: 5.4879x; 5.4879x over previous
//
#include <hip/hip_runtime.h>

// VectorQuantizer forward: out = codebook[argmin_k ||x - e_k||^2]
// R15: 32x32x16 MFMA shape. R14 (full unroll) spilled catastrophically
//      (WRITE 745 MB: compiler hoisted all 128 ds_reads) -> reverted to
//      R10's loop form. R9-R14 establish: wall ~58-60 us invariant to
//      occupancy / prefetch / scheduling; busy ~18 us, stall ~40 us. Last
//      untested lever: per-wave serial structure via MFMA shape. 32x32x16
//      (C/D: col=lane&31, row=(reg&3)+8*(reg>>2)+4*(lane>>5); A/B:
//      row/col=lane&31, k=(lane>>5)*8+j) halves MFMA instruction count at
//      the faster 32x32 rate, and rt=2 B-reuse halves per-wave ds_reads
//      (8 b128 feed 24 MFMA). Numerics identical to R10: 3-term bf16 split
//      (lo*lo dropped, err ~4e-5), strict-gt first-min argmin, exact fp32
//      fallback for best1/best2 c-gap <= TAU/2 => committed argmins
//      provably identical to fp32 path.

#define KC 512
#define DD 64
#define TAU 5e-4f
#define HTAU (0.5f * TAU)    // threshold in c-space (s = -2c)

typedef __attribute__((ext_vector_type(8))) short short8;
typedef __attribute__((ext_vector_type(4))) float float4v;
typedef __attribute__((ext_vector_type(16))) float f32x16;

__device__ inline unsigned short f2bf(float f) {   // RNE bf16
    unsigned u = __float_as_uint(f);
    return (unsigned short)((u + 0x7FFF + ((u >> 16) & 1)) >> 16);
}
__device__ inline float bf2f(unsigned short b) {
    return __uint_as_float((unsigned)b << 16);
}

// Per 32-code tile ctt (0..15): bias (exact fp32, sequential d), et (fp32
// transposed codebook for gather/fallback), and Bh/Bl bf16 packs laid out in
// the exact 32x32x16 B-fragment order: element (lane l, j) of chunk kc =
// E[kc*16 + (l>>5)*8 + j][ctt*32 + (l&31)].
__global__ __launch_bounds__(256) void vq_prep(const float* __restrict__ emb,
                                               float* __restrict__ et,
                                               float* __restrict__ bias,
                                               short* __restrict__ Bh,
                                               short* __restrict__ Bl) {
    __shared__ float tile[DD][33];
    const int ctt = blockIdx.x;           // 0..15
    const int t   = threadIdx.x;

    {   // stage emb[d][ctt*32..+32] -> tile[d][c]
        const int d = t >> 2, c0 = (t & 3) * 8;
        float4 v0 = *(const float4*)(emb + (size_t)d * KC + ctt * 32 + c0);
        float4 v1 = *(const float4*)(emb + (size_t)d * KC + ctt * 32 + c0 + 4);
        tile[d][c0 + 0] = v0.x; tile[d][c0 + 1] = v0.y;
        tile[d][c0 + 2] = v0.z; tile[d][c0 + 3] = v0.w;
        tile[d][c0 + 4] = v1.x; tile[d][c0 + 5] = v1.y;
        tile[d][c0 + 6] = v1.z; tile[d][c0 + 7] = v1.w;
    }
    __syncthreads();

    if (t < 32) {   // bias, exact sequential d-order
        float s = 0.f;
        #pragma unroll
        for (int d = 0; d < DD; ++d) { float v = tile[d][t]; s += v * v; }
        bias[ctt * 32 + t] = s;
    }

    {   // et[(ctt*32+c)][d0..d0+8]
        const int c = t >> 3, d0 = (t & 7) * 8;
        float4 v0, v1;
        v0.x = tile[d0 + 0][c]; v0.y = tile[d0 + 1][c];
        v0.z = tile[d0 + 2][c]; v0.w = tile[d0 + 3][c];
        v1.x = tile[d0 + 4][c]; v1.y = tile[d0 + 5][c];
        v1.z = tile[d0 + 6][c]; v1.w = tile[d0 + 7][c];
        *(float4*)(et + (size_t)(ctt * 32 + c) * DD + d0)     = v0;
        *(float4*)(et + (size_t)(ctt * 32 + c) * DD + d0 + 4) = v1;
    }

    {   // B-fragment packs: 512 (term,kc,lane) slots over 256 threads x 2
        #pragma unroll
        for (int pass = 0; pass < 2; ++pass) {
            const int idx  = pass * 256 + t;
            const int term = idx >> 8;            // 0 = hi, 1 = lo
            const int kc   = (idx >> 6) & 3;
            const int l    = idx & 63;
            const int c    = l & 31, hg = l >> 5;
            short v8[8];
            #pragma unroll
            for (int j = 0; j < 8; ++j) {
                float f = tile[kc * 16 + hg * 8 + j][c];
                unsigned short h = f2bf(f);
                v8[j] = (short)(term == 0 ? h : f2bf(f - bf2f(h)));
            }
            short* dst = (term == 0 ? Bh : Bl) + ((size_t)(ctt * 4 + kc) * 64 + l) * 8;
            *(short8*)dst = *(short8*)v8;
        }
    }
}

// Block = 512 threads / 8 waves, covers 512 rows; wave w owns rows
// [w*64, w*64+64) as two 32-row A tiles in registers, sweeps 512 codes
// from LDS in 16 tiles of 32.
__global__ __launch_bounds__(512, 2) void vq_main(const float* __restrict__ x_in,
                                                  const short* __restrict__ Bh,
                                                  const short* __restrict__ Bl,
                                                  const float* __restrict__ bias,
                                                  const float* __restrict__ et,
                                                  float* __restrict__ out) {
    __shared__ __align__(16) short Bh_lds[16 * 4 * 64 * 8];   // 64 KB
    __shared__ __align__(16) short Bl_lds[16 * 4 * 64 * 8];   // 64 KB
    __shared__ float bias_s[KC];                               // 2 KB
    __shared__ int   k1s[8][64];
    __shared__ float gaps[8][64];

    const int t = threadIdx.x, w = t >> 6, l = t & 63;
    const int c32 = l & 31, hg = l >> 5;       // 32x32 fragment coords
    const int col = l & 15, quad = l >> 4;     // epilogue coords
    const int R0 = blockIdx.x * 512;
    const int wrow0 = w * 64;

    {   // stage Bh/Bl/bias -> LDS (coalesced float4 copies)
        const float4* srcH = (const float4*)Bh;
        const float4* srcL = (const float4*)Bl;
        float4* dstH = (float4*)Bh_lds;
        float4* dstL = (float4*)Bl_lds;
        #pragma unroll
        for (int j = 0; j < 8; ++j) {
            const int idx = t + j * 512;              // 4096 float4 per array
            dstH[idx] = srcH[idx];
            dstL[idx] = srcL[idx];
        }
        bias_s[t] = bias[t];
    }

    // ---- A: this wave's 64 rows -> registers, bf16 hi/lo split (once).
    // 32x32x16 A-layout: row = lane&31, k = (lane>>5)*8 + j, chunk kc*16.
    short8 AH[2][4], AL[2][4];
    #pragma unroll
    for (int rt = 0; rt < 2; ++rt)
        #pragma unroll
        for (int kc = 0; kc < 4; ++kc) {
            const float* p = x_in + (size_t)(R0 + wrow0 + rt * 32 + c32) * DD
                           + kc * 16 + hg * 8;
            float4 xa = *(const float4*)p;
            float4 xb = *(const float4*)(p + 4);
            float f[8] = {xa.x, xa.y, xa.z, xa.w, xb.x, xb.y, xb.z, xb.w};
            short8 hi8, lo8;
            #pragma unroll
            for (int j = 0; j < 8; ++j) {
                unsigned short h = f2bf(f[j]);
                hi8[j] = (short)h;
                lo8[j] = (short)f2bf(f[j] - bf2f(h));
            }
            AH[rt][kc] = hi8;
            AL[rt][kc] = lo8;
        }
    __syncthreads();   // B staged (the only block-wide barrier before reduce)

    // per-(row,code-lane) running max1/max2/k in c-space (c = x.e - b/2)
    float m1[2][16], m2[2][16];
    int   kb[2][16];
    #pragma unroll
    for (int rt = 0; rt < 2; ++rt)
        #pragma unroll
        for (int r = 0; r < 16; ++r) {
            m1[rt][r] = -3.4e38f; m2[rt][r] = -3.4e38f; kb[rt][r] = 0;
        }

    #pragma unroll 2
    for (int ctt = 0; ctt < 16; ++ctt) {
        short8 bh[4], bl[4];
        #pragma unroll
        for (int kc = 0; kc < 4; ++kc) {
            bh[kc] = *(const short8*)&Bh_lds[((ctt * 4 + kc) * 64 + l) * 8];
            bl[kc] = *(const short8*)&Bl_lds[((ctt * 4 + kc) * 64 + l) * 8];
        }
        const float ci = -0.5f * bias_s[ctt * 32 + c32];
        const int kk = ctt * 32 + c32;
        #pragma unroll
        for (int rt = 0; rt < 2; ++rt) {
            f32x16 c;
            #pragma unroll
            for (int r = 0; r < 16; ++r) c[r] = ci;
            #pragma unroll
            for (int kc = 0; kc < 4; ++kc)
                c = __builtin_amdgcn_mfma_f32_32x32x16_bf16(AH[rt][kc], bh[kc], c, 0, 0, 0);
            #pragma unroll
            for (int kc = 0; kc < 4; ++kc)
                c = __builtin_amdgcn_mfma_f32_32x32x16_bf16(AL[rt][kc], bh[kc], c, 0, 0, 0);
            #pragma unroll
            for (int kc = 0; kc < 4; ++kc)
                c = __builtin_amdgcn_mfma_f32_32x32x16_bf16(AH[rt][kc], bl[kc], c, 0, 0, 0);
            #pragma unroll
            for (int r = 0; r < 16; ++r) {
                float cr = c[r];
                bool gt = cr > m1[rt][r];                    // strict: first-min k
                m2[rt][r] = fmaxf(fminf(cr, m1[rt][r]), m2[rt][r]);
                kb[rt][r] = gt ? kk : kb[rt][r];
                m1[rt][r] = fmaxf(m1[rt][r], cr);
            }
        }
    }

    // reduce over the 32 code-lanes (once per wave); C layout: col=lane&31,
    // row = (r&3) + 8*(r>>2) + 4*(lane>>5), within tile rt.
    #pragma unroll
    for (int rt = 0; rt < 2; ++rt)
        #pragma unroll
        for (int r = 0; r < 16; ++r) {
            float b1 = m1[rt][r], b2 = m2[rt][r];
            int   bk = kb[rt][r];
            #pragma unroll
            for (int m = 1; m <= 16; m <<= 1) {
                float o1 = __shfl_xor(b1, m, 64);
                float o2 = __shfl_xor(b2, m, 64);
                int   ok = __shfl_xor(bk, m, 64);
                float n2 = fmaxf(fmaxf(b2, o2), fminf(b1, o1));
                bool take = (o1 > b1) || (o1 == b1 && ok < bk);
                b1 = take ? o1 : b1;
                bk = take ? ok : bk;
                b2 = n2;
            }
            if (c32 == 0) {
                const int rowl = rt * 32 + (r & 3) + 8 * (r >> 2) + 4 * hg;
                k1s[w][rowl]  = bk;
                gaps[w][rowl] = b1 - b2;     // c-space gap = s-gap / 2
            }
        }
    __syncthreads();   // make k1s/gaps visible (cheap, once)

    {   // exact fp32 fallback for near-tie rows (ballot-driven, rare).
        // Lane l scans codes [8l,8l+8) ascending; cross-lane tie-break =
        // lower k => numpy first-min semantics, independent of approx path.
        unsigned long long mask = __ballot(gaps[w][l] <= HTAU);
        while (mask) {
            const int rr = __builtin_ctzll(mask);
            mask &= mask - 1;
            const size_t grow = (size_t)(R0 + wrow0 + rr) * DD;
            const int kbase = l * 8;
            float acc[8];
            #pragma unroll
            for (int j = 0; j < 8; ++j) acc[j] = 0.f;
            for (int d0 = 0; d0 < DD; d0 += 4) {
                float4 xv = *(const float4*)(x_in + grow + d0);
                #pragma unroll
                for (int j = 0; j < 8; ++j) {
                    float4 ev = *(const float4*)(et + (size_t)(kbase + j) * DD + d0);
                    acc[j] += xv.x * ev.x;
                    acc[j] += xv.y * ev.y;
                    acc[j] += xv.z * ev.z;
                    acc[j] += xv.w * ev.w;
                }
            }
            float4 b0 = *(const float4*)(bias + kbase);
            float4 b1v = *(const float4*)(bias + kbase + 4);
            float bb[8] = {b0.x, b0.y, b0.z, b0.w, b1v.x, b1v.y, b1v.z, b1v.w};
            float bv = 3.4e38f; int bk = 0;
            #pragma unroll
            for (int j = 0; j < 8; ++j) {
                float s = bb[j] - 2.f * acc[j];
                if (s < bv) { bv = s; bk = kbase + j; }
            }
            #pragma unroll
            for (int m = 1; m <= 32; m <<= 1) {
                float ov = __shfl_xor(bv, m, 64);
                int   ok = __shfl_xor(bk, m, 64);
                if (ov < bv || (ov == bv && ok < bk)) { bv = ov; bk = ok; }
            }
            if (l == 0) k1s[w][rr] = bk;
        }
    }

    {   // gather epilogue (per wave, its own 64 rows): 16 lanes per row
        const int c4 = col * 4;
        #pragma unroll
        for (int i = 0; i < 16; ++i) {
            const int rowl = i * 4 + quad;
            const int bk = k1s[w][rowl];
            float4 v = *(const float4*)(et + (size_t)bk * DD + c4);
            *(float4*)(out + (size_t)(R0 + wrow0 + rowl) * DD + c4) = v;
        }
    }
}

extern "C" void kernel_launch(void* const* d_in, const int* in_sizes, int n_in,
                              void* d_out, int out_size, void* d_ws, size_t ws_size,
                              hipStream_t stream) {
    const float* x_in = (const float*)d_in[0];   // [131072, 64]
    const float* emb  = (const float*)d_in[1];   // [64, 512]
    float* out = (float*)d_out;

    float* et   = (float*)d_ws;                       // 512*64 f32 = 131072 B
    float* bias = et + KC * DD;                       // 2048 B
    short* Bh   = (short*)(bias + KC);                // 16*4*64*8 shorts = 64 KB
    short* Bl   = Bh + 16 * 4 * 64 * 8;               // 64 KB

    const int N = out_size / DD;                      // 131072 rows

    vq_prep<<<16, 256, 0, stream>>>(emb, et, bias, Bh, Bl);
    vq_main<<<N / 512, 512, 0, stream>>>(x_in, Bh, Bl, bias, et, out);
}

// Round 10
// 125.397 us; speedup vs baseline: 6.1505x; 1.1207x over previous
//
#include <hip/hip_runtime.h>

// VectorQuantizer forward: out = codebook[argmin_k ||x - e_k||^2]
// R16: wave-skewed sweep. R15 (32x32 shape) spilled (WRITE 47 MB) ->
//      discarded; R10 16x16 config restored byte-for-byte. R9-R15
//      establish: 58-60 us invariant to occupancy/prefetch/ILP/shape;
//      serial pipe sum is only ~26 us -> the 2x residue is convoy stall:
//      all 16 waves run the identical stream from one barrier, so LDS /
//      MFMA / VALU phases alternate chip-wide instead of overlapping.
//      Fix (zero-cost): wave w sweeps code-tiles in rotated order
//      ct = (i + 2w) & 31 -> at any instant waves occupy different phases
//      and all three pipes are fed. Reordering is provably safe: max/2nd-max
//      are order-independent; the argmax is order-dependent only on exact
//      ties, which have gap=0 <= HTAU and are repaired by the unchanged
//      exact-fp32 first-min fallback. Numerics identical to R10 (3-term
//      bf16 split, strict-gt argmin, TAU fallback) => committed argmins
//      provably identical to fp32 path.

#define KC 512
#define DD 64
#define TAU 5e-4f
#define HTAU (0.5f * TAU)    // threshold in c-space (s = -2c)

typedef __attribute__((ext_vector_type(8))) short short8;
typedef __attribute__((ext_vector_type(4))) float float4v;

__device__ inline unsigned short f2bf(float f) {   // RNE bf16
    unsigned u = __float_as_uint(f);
    return (unsigned short)((u + 0x7FFF + ((u >> 16) & 1)) >> 16);
}
__device__ inline float bf2f(unsigned short b) {
    return __uint_as_float((unsigned)b << 16);
}

// Per code-tile ct (16 codes): bias (exact fp32, sequential d), et (fp32
// transposed codebook for gather/fallback), and Bh/Bl bf16 packs laid out in
// the exact 16x16x32 B-fragment order: element (lane l, j) = E[kc*32 +
// (l>>4)*8 + j][ct*16 + (l&15)].
__global__ __launch_bounds__(256) void vq_prep(const float* __restrict__ emb,
                                               float* __restrict__ et,
                                               float* __restrict__ bias,
                                               short* __restrict__ Bh,
                                               short* __restrict__ Bl) {
    __shared__ float tile[DD][17];
    const int ct = blockIdx.x;            // 0..31
    const int t  = threadIdx.x;

    {   // stage emb[d][ct*16..+16] -> tile[d][c]
        const int d = t >> 2, c0 = (t & 3) * 4;
        float4 v = *(const float4*)(emb + (size_t)d * KC + ct * 16 + c0);
        tile[d][c0 + 0] = v.x; tile[d][c0 + 1] = v.y;
        tile[d][c0 + 2] = v.z; tile[d][c0 + 3] = v.w;
    }
    __syncthreads();

    if (t < 16) {   // bias, exact sequential d-order
        float s = 0.f;
        #pragma unroll
        for (int d = 0; d < DD; ++d) { float v = tile[d][t]; s += v * v; }
        bias[ct * 16 + t] = s;
    }

    {   // et[(ct*16+c)][d0..d0+3]
        const int c = t >> 4, d0 = (t & 15) * 4;
        float4 v;
        v.x = tile[d0 + 0][c]; v.y = tile[d0 + 1][c];
        v.z = tile[d0 + 2][c]; v.w = tile[d0 + 3][c];
        *(float4*)(et + (size_t)(ct * 16 + c) * DD + d0) = v;
    }

    {   // B-fragment packs
        const int term = t >> 7;          // 0 = hi, 1 = lo
        const int kc   = (t >> 6) & 1;
        const int l    = t & 63;
        const int c    = l & 15, dq = l >> 4;
        short v8[8];
        #pragma unroll
        for (int j = 0; j < 8; ++j) {
            float f = tile[kc * 32 + dq * 8 + j][c];
            unsigned short h = f2bf(f);
            v8[j] = (short)(term == 0 ? h : f2bf(f - bf2f(h)));
        }
        short* dst = (term == 0 ? Bh : Bl) + ((size_t)(ct * 2 + kc) * 64 + l) * 8;
        *(short8*)dst = *(short8*)v8;
    }
}

// Block = 1024 threads / 16 waves, covers 512 rows; wave w owns rows
// [w*32, w*32+32) in registers and sweeps all 512 codes from LDS in a
// wave-rotated order.
__global__ __launch_bounds__(1024, 4) void vq_main(const float* __restrict__ x_in,
                                                   const short* __restrict__ Bh,
                                                   const short* __restrict__ Bl,
                                                   const float* __restrict__ bias,
                                                   const float* __restrict__ et,
                                                   float* __restrict__ out) {
    __shared__ __align__(16) short Bh_lds[32 * 2 * 64 * 8];   // 64 KB
    __shared__ __align__(16) short Bl_lds[32 * 2 * 64 * 8];   // 64 KB
    __shared__ float bias_s[KC];                               // 2 KB
    __shared__ int   k1s[16][32];
    __shared__ float gaps[16][32];

    const int t = threadIdx.x, w = t >> 6, l = t & 63;
    const int col = l & 15, quad = l >> 4;
    const int R0 = blockIdx.x * 512;
    const int wrow0 = w * 32;

    {   // stage Bh/Bl/bias -> LDS (coalesced float4 copies)
        const float4* srcH = (const float4*)Bh;
        const float4* srcL = (const float4*)Bl;
        float4* dstH = (float4*)Bh_lds;
        float4* dstL = (float4*)Bl_lds;
        #pragma unroll
        for (int j = 0; j < 4; ++j) {
            const int idx = t + j * 1024;             // 4096 float4 per array
            dstH[idx] = srcH[idx];
            dstL[idx] = srcL[idx];
        }
        if (t < KC) bias_s[t] = bias[t];
    }

    // ---- A: this wave's 32 rows -> registers, bf16 hi/lo split (done once).
    // 16x16x32 A-layout: m = lane&15, k = quad*8 + j; rt = 16-row tile 0..1.
    short8 AH[2][2], AL[2][2];
    #pragma unroll
    for (int rt = 0; rt < 2; ++rt)
        #pragma unroll
        for (int kc = 0; kc < 2; ++kc) {
            const float* p = x_in + (size_t)(R0 + wrow0 + rt * 16 + col) * DD
                           + kc * 32 + quad * 8;
            float4 xa = *(const float4*)p;
            float4 xb = *(const float4*)(p + 4);
            float f[8] = {xa.x, xa.y, xa.z, xa.w, xb.x, xb.y, xb.z, xb.w};
            short8 hi8, lo8;
            #pragma unroll
            for (int j = 0; j < 8; ++j) {
                unsigned short h = f2bf(f[j]);
                hi8[j] = (short)h;
                lo8[j] = (short)f2bf(f[j] - bf2f(h));
            }
            AH[rt][kc] = hi8;
            AL[rt][kc] = lo8;
        }
    __syncthreads();   // B staged (the only block-wide barrier before reduce)

    // per-(row,code-lane) running max1/max2/k in c-space (c = x.e - b/2)
    float m1[2][4], m2[2][4];
    int   kb[2][4];
    #pragma unroll
    for (int rt = 0; rt < 2; ++rt)
        #pragma unroll
        for (int r = 0; r < 4; ++r) {
            m1[rt][r] = -3.4e38f; m2[rt][r] = -3.4e38f; kb[rt][r] = 0;
        }

    // ---- wave-skewed sweep: wave w starts at tile 2w and wraps. Breaks the
    // 16-wave convoy so LDS / MFMA / VALU phases overlap across waves.
    const int ct0 = 2 * w;
    #pragma unroll 2
    for (int i = 0; i < 32; ++i) {
        const int ct = (i + ct0) & 31;
        short8 bh0 = *(const short8*)&Bh_lds[((ct * 2 + 0) * 64 + l) * 8];
        short8 bh1 = *(const short8*)&Bh_lds[((ct * 2 + 1) * 64 + l) * 8];
        short8 bl0 = *(const short8*)&Bl_lds[((ct * 2 + 0) * 64 + l) * 8];
        short8 bl1 = *(const short8*)&Bl_lds[((ct * 2 + 1) * 64 + l) * 8];
        const float ci = -0.5f * bias_s[ct * 16 + col];
        const int kk = ct * 16 + col;
        #pragma unroll
        for (int rt = 0; rt < 2; ++rt) {
            float4v c = {ci, ci, ci, ci};
            c = __builtin_amdgcn_mfma_f32_16x16x32_bf16(AH[rt][0], bh0, c, 0, 0, 0);
            c = __builtin_amdgcn_mfma_f32_16x16x32_bf16(AH[rt][1], bh1, c, 0, 0, 0);
            c = __builtin_amdgcn_mfma_f32_16x16x32_bf16(AL[rt][0], bh0, c, 0, 0, 0);
            c = __builtin_amdgcn_mfma_f32_16x16x32_bf16(AL[rt][1], bh1, c, 0, 0, 0);
            c = __builtin_amdgcn_mfma_f32_16x16x32_bf16(AH[rt][0], bl0, c, 0, 0, 0);
            c = __builtin_amdgcn_mfma_f32_16x16x32_bf16(AH[rt][1], bl1, c, 0, 0, 0);
            #pragma unroll
            for (int r = 0; r < 4; ++r) {
                float cr = c[r];
                bool gt = cr > m1[rt][r];        // strict: unique-max safe
                m2[rt][r] = fmaxf(fminf(cr, m1[rt][r]), m2[rt][r]);
                kb[rt][r] = gt ? kk : kb[rt][r];
                m1[rt][r] = fmaxf(m1[rt][r], cr);
            }
        }
    }

    // reduce over the 16 code-lanes (once per wave); C layout: row =
    // rt*16 + quad*4 + r, col = lane&15.
    #pragma unroll
    for (int rt = 0; rt < 2; ++rt)
        #pragma unroll
        for (int r = 0; r < 4; ++r) {
            float b1 = m1[rt][r], b2 = m2[rt][r];
            int   bk = kb[rt][r];
            #pragma unroll
            for (int m = 1; m <= 8; m <<= 1) {
                float o1 = __shfl_xor(b1, m, 64);
                float o2 = __shfl_xor(b2, m, 64);
                int   ok = __shfl_xor(bk, m, 64);
                float n2 = fmaxf(fmaxf(b2, o2), fminf(b1, o1));
                bool take = (o1 > b1) || (o1 == b1 && ok < bk);
                b1 = take ? o1 : b1;
                bk = take ? ok : bk;
                b2 = n2;
            }
            if (col == 0) {
                const int rowl = rt * 16 + quad * 4 + r;
                k1s[w][rowl]  = bk;
                gaps[w][rowl] = b1 - b2;     // c-space gap = s-gap / 2
            }
        }
    __syncthreads();   // make k1s/gaps visible (cheap, once)

    {   // exact fp32 fallback for near-tie rows (ballot-driven, rare).
        // Lane l scans codes [8l,8l+8) ascending; cross-lane tie-break =
        // lower k => numpy first-min semantics, independent of approx path.
        unsigned long long mask = __ballot((l < 32) && (gaps[w][l & 31] <= HTAU));
        mask &= 0xFFFFFFFFull;
        while (mask) {
            const int rr = __builtin_ctzll(mask);
            mask &= mask - 1;
            const size_t grow = (size_t)(R0 + wrow0 + rr) * DD;
            const int kbase = l * 8;
            float acc[8];
            #pragma unroll
            for (int j = 0; j < 8; ++j) acc[j] = 0.f;
            for (int d0 = 0; d0 < DD; d0 += 4) {
                float4 xv = *(const float4*)(x_in + grow + d0);
                #pragma unroll
                for (int j = 0; j < 8; ++j) {
                    float4 ev = *(const float4*)(et + (size_t)(kbase + j) * DD + d0);
                    acc[j] += xv.x * ev.x;
                    acc[j] += xv.y * ev.y;
                    acc[j] += xv.z * ev.z;
                    acc[j] += xv.w * ev.w;
                }
            }
            float4 b0 = *(const float4*)(bias + kbase);
            float4 b1v = *(const float4*)(bias + kbase + 4);
            float bb[8] = {b0.x, b0.y, b0.z, b0.w, b1v.x, b1v.y, b1v.z, b1v.w};
            float bv = 3.4e38f; int bk = 0;
            #pragma unroll
            for (int j = 0; j < 8; ++j) {
                float s = bb[j] - 2.f * acc[j];
                if (s < bv) { bv = s; bk = kbase + j; }
            }
            #pragma unroll
            for (int m = 1; m <= 32; m <<= 1) {
                float ov = __shfl_xor(bv, m, 64);
                int   ok = __shfl_xor(bk, m, 64);
                if (ov < bv || (ov == bv && ok < bk)) { bv = ov; bk = ok; }
            }
            if (l == 0) k1s[w][rr] = bk;
        }
    }

    {   // gather epilogue (per wave, its own rows): 16 lanes per row
        const int c4 = col * 4;
        #pragma unroll
        for (int i = 0; i < 8; ++i) {
            const int rowl = i * 4 + quad;
            const int bk = k1s[w][rowl];
            float4 v = *(const float4*)(et + (size_t)bk * DD + c4);
            *(float4*)(out + (size_t)(R0 + wrow0 + rowl) * DD + c4) = v;
        }
    }
}

extern "C" void kernel_launch(void* const* d_in, const int* in_sizes, int n_in,
                              void* d_out, int out_size, void* d_ws, size_t ws_size,
                              hipStream_t stream) {
    const float* x_in = (const float*)d_in[0];   // [131072, 64]
    const float* emb  = (const float*)d_in[1];   // [64, 512]
    float* out = (float*)d_out;

    float* et   = (float*)d_ws;                       // 512*64 f32 = 131072 B
    float* bias = et + KC * DD;                       // 2048 B
    short* Bh   = (short*)(bias + KC);                // 32*2*64*8 shorts = 64 KB
    short* Bl   = Bh + 32 * 2 * 64 * 8;               // 64 KB

    const int N = out_size / DD;                      // 131072 rows

    vq_prep<<<32, 256, 0, stream>>>(emb, et, bias, Bh, Bl);
    vq_main<<<N / 512, 1024, 0, stream>>>(x_in, Bh, Bl, bias, et, out);
}